// Round 11
// baseline (370.697 us; speedup 1.0000x reference)
//
#include <hip/hip_runtime.h>
#include <math.h>

#define H_HEADS 33
#define C_CH    16
#define HC      528      // H_HEADS * C_CH
#define JG      11       // head groups of 3 (48 cols each) for h
#define JGT     13       // + 2 groups: att_src logits, att_dst logits
#define F_IN    128
#define NEG_SLOPE 0.2f

#define BSH   7          // bucket = id >> 7 (128 ids/bucket)
#define BMAX  1024       // max buckets supported (N <= 131072)
#define PCH   4096       // edges per partition block
#define DCAP  3072       // LDS mirror capacity in p2 (mean bucket ~946)

typedef short  bf16x8  __attribute__((ext_vector_type(8)));
typedef float  floatx4 __attribute__((ext_vector_type(4)));
typedef float  floatx2 __attribute__((ext_vector_type(2)));

__device__ inline unsigned short f2bf(float f) {   // RNE float->bf16
    unsigned int u = __float_as_uint(f);
    unsigned int r = u + 0x7fffu + ((u >> 16) & 1u);
    return (unsigned short)(r >> 16);
}
__device__ inline float bflo(unsigned int u) {
    return __uint_as_float(u << 16);
}
__device__ inline float bfhi(unsigned int u) {
    return __uint_as_float(u & 0xffff0000u);
}

// Load 4 consecutive (src,dst) edge pairs (self-loops appended past E).
// Sentinel -1 past Et.
__device__ inline void load_edges4(const int* __restrict__ ei, int E, int Et,
                                   int e0, int* src, int* dst)
{
    if (e0 + 3 < E) {
        int4 s4 = *(const int4*)&ei[e0];
        src[0] = s4.x; src[1] = s4.y; src[2] = s4.z; src[3] = s4.w;
        if ((E & 3) == 0) {
            int4 d4 = *(const int4*)&ei[E + e0];
            dst[0] = d4.x; dst[1] = d4.y; dst[2] = d4.z; dst[3] = d4.w;
        } else {
            #pragma unroll
            for (int k = 0; k < 4; ++k) dst[k] = ei[E + e0 + k];
        }
    } else {
        #pragma unroll
        for (int k = 0; k < 4; ++k) {
            int g = e0 + k;
            if (g < E)       { src[k] = ei[g]; dst[k] = ei[E + g]; }
            else if (g < Et) { src[k] = dst[k] = g - E; }
            else             { src[k] = dst[k] = -1; }
        }
    }
}

// ---------------------------------------------------------------------------
// K0: prep. (a) Wt[0..527] = bf16(W^T); (b) rows 528..623 = attention-logit
// GEMM columns; (c) zero out; (d) bucket histograms (4 edges/thread, 8
// independent global atomics; bhist pre-zeroed by an 8KB memset).
// ---------------------------------------------------------------------------
#define PW1 (F_IN * HC)        // 67584
#define PW2 (PW1 + 96 * F_IN)  // 79872
__global__ void prep_kernel(const float* __restrict__ W,
                            const float* __restrict__ att_src,
                            const float* __restrict__ att_dst,
                            unsigned short* __restrict__ Wt,
                            float4* __restrict__ zout, int nzo,
                            const int* __restrict__ ei,
                            int* __restrict__ bhist, int E, int Et)
{
    int g = blockIdx.x * blockDim.x + threadIdx.x;
    if (g < PW1) {
        int k = g / HC, n = g % HC;
        Wt[n * F_IN + k] = f2bf(W[g]);
    } else if (g < PW2) {
        int gg = g - PW1;
        int nl = gg >> 7, k = gg & 127;
        int grp = nl / 48, h = nl % 48;
        float v = 0.f;
        if (h < H_HEADS) {
            const float* att = grp ? att_dst : att_src;
            const float* wr  = W + (size_t)k * HC + h * C_CH;
            #pragma unroll
            for (int c = 0; c < C_CH; ++c) v += wr[c] * att[h * C_CH + c];
        }
        Wt[(size_t)(HC + nl) * F_IN + k] = f2bf(v);
    } else {
        int z = g - PW2;
        if (z < nzo) {
            zout[z] = make_float4(0.f, 0.f, 0.f, 0.f);
        } else {
            int e0 = (z - nzo) * 4;
            if (e0 < Et) {
                int s4[4], d4[4];
                load_edges4(ei, E, Et, e0, s4, d4);
                #pragma unroll
                for (int k = 0; k < 4; ++k)
                    if (s4[k] >= 0) {
                        atomicAdd(&bhist[s4[k] >> BSH], 1);
                        atomicAdd(&bhist[BMAX + (d4[k] >> BSH)], 1);
                    }
            }
        }
    }
}

// ---------------------------------------------------------------------------
// K1: h = x @ W via MFMA 16x16x32 bf16. As/Bs share one LDS buffer (As dead
// after A-fragment extraction): 17.4KB -> 8 blocks/CU. Bs staging register
// double-buffered. Groups 0..10 -> hb column-blocked [j][row][48];
// 11 -> a_src; 12 -> a_dstc.
// ---------------------------------------------------------------------------
#define LDA 136
__global__ __launch_bounds__(256) void gemm_att_kernel(
    const float* __restrict__ x, const unsigned short* __restrict__ Wt,
    unsigned short* __restrict__ hb,
    float* __restrict__ a_src, float* __restrict__ a_dstc, int N)
{
    __shared__ unsigned short U[64 * LDA];   // As (prologue) then Bs (loop)
    unsigned short (*As)[LDA] = (unsigned short (*)[LDA])U;
    unsigned short (*Bs)[LDA] = (unsigned short (*)[LDA])U;

    const int tid  = threadIdx.x;
    const int lane = tid & 63;
    const int wave = tid >> 6;
    const int lm   = lane & 15;
    const int kc   = lane >> 4;
    const int m0   = blockIdx.x * 64;
    const size_t segN = (size_t)N * 48;

    // stage As from f32 x, converting: 64 rows x 32 float4 chunks
    for (int e = tid; e < 64 * 32; e += 256) {
        int r = e >> 5, c = e & 31;
        int gr = m0 + r;
        float4 v = (gr < N) ? ((const float4*)(x + (size_t)gr * F_IN))[c]
                            : make_float4(0.f, 0.f, 0.f, 0.f);
        unsigned int lo = (unsigned int)f2bf(v.x) | ((unsigned int)f2bf(v.y) << 16);
        unsigned int hi = (unsigned int)f2bf(v.z) | ((unsigned int)f2bf(v.w) << 16);
        *(uint2*)&As[r][c * 4] = make_uint2(lo, hi);
    }

    // prefetch j=0 B-tile into registers (Wt rows are contiguous uint4s)
    const uint4* wp = (const uint4*)Wt;
    uint4 rb0 = wp[tid], rb1 = wp[tid + 256], rb2 = wp[tid + 512];

    __syncthreads();

    // A fragments to registers; As LDS space is dead after this (barrier at
    // the top of the j-loop orders these reads before the Bs overwrite)
    const int arow = wave * 16 + lm;
    bf16x8 afrag[4];
    #pragma unroll
    for (int ks = 0; ks < 4; ++ks)
        afrag[ks] = *(const bf16x8*)&As[arow][ks * 32 + kc * 8];

    #pragma unroll 1
    for (int j = 0; j < JGT; ++j) {
        __syncthreads();   // prev iter's Bs reads (and prologue As reads) done
        *(uint4*)&Bs[tid >> 4][(tid & 15) * 8] = rb0;
        { int e = tid + 256; *(uint4*)&Bs[e >> 4][(e & 15) * 8] = rb1; }
        { int e = tid + 512; *(uint4*)&Bs[e >> 4][(e & 15) * 8] = rb2; }
        if (j + 1 < JGT) {
            int b = (j + 1) * 768;
            rb0 = wp[b + tid]; rb1 = wp[b + tid + 256]; rb2 = wp[b + tid + 512];
        }
        __syncthreads();

        floatx4 acc[3] = {};
        #pragma unroll
        for (int ks = 0; ks < 4; ++ks) {
            #pragma unroll
            for (int t = 0; t < 3; ++t) {
                bf16x8 b = *(const bf16x8*)&Bs[t * 16 + lm][ks * 32 + kc * 8];
                acc[t] = __builtin_amdgcn_mfma_f32_16x16x32_bf16(afrag[ks], b, acc[t], 0, 0, 0);
            }
        }

        // C/D layout: col = lane&15, row = (lane>>4)*4 + reg
        #pragma unroll
        for (int t = 0; t < 3; ++t) {
            #pragma unroll
            for (int rr = 0; rr < 4; ++rr) {
                const int row = m0 + wave * 16 + kc * 4 + rr;
                if (row >= N) continue;
                if (j < JG) {
                    hb[(size_t)j * segN + (size_t)row * 48 + t * 16 + lm] =
                        f2bf(acc[t][rr]);
                } else {
                    const int col = t * 16 + lm;
                    if (col < H_HEADS) {
                        float* dstp = (j == JG) ? a_src : a_dstc;
                        dstp[(size_t)row * H_HEADS + col] = acc[t][rr];
                    }
                }
            }
        }
    }
}

// ---------------------------------------------------------------------------
// Bucket scan: grid=2 (side 0 = src, side 1 = dst).
// ---------------------------------------------------------------------------
__global__ __launch_bounds__(1024) void scanb_kernel(const int* __restrict__ bhist,
                                                     int* __restrict__ bbase,
                                                     int* __restrict__ cursor,
                                                     int nb)
{
    const int side = blockIdx.x;
    const int tid  = threadIdx.x;
    const int* h = bhist + side * BMAX;
    int* bb  = bbase  + side * (BMAX + 1);
    int* cur = cursor + side * BMAX;
    __shared__ int sa[1024];
    int v = (tid < nb) ? h[tid] : 0;
    sa[tid] = v;
    __syncthreads();
    for (int off = 1; off < 1024; off <<= 1) {
        int t = (tid >= off) ? sa[tid - off] : 0;
        __syncthreads();
        sa[tid] += t;
        __syncthreads();
    }
    int incl = sa[tid];
    if (tid < nb) {
        bb[tid]  = incl - v;
        cur[tid] = incl - v;
        if (tid == nb - 1) bb[nb] = incl;
    }
}

// ---------------------------------------------------------------------------
// Partition pass: block takes PCH edges, groups by bucket in LDS, reserves
// per-bucket global space (one atomic per block-bucket), writes groups
// contiguously (full sectors).
// ---------------------------------------------------------------------------
__global__ __launch_bounds__(256) void part_kernel(const int* __restrict__ ei,
                                                   int* __restrict__ cursor,
                                                   int2* __restrict__ Ag,
                                                   int E, int Et)
{
    __shared__ int2 kv[PCH];
    __shared__ int  lhist[512];
    __shared__ int  gbias[512];
    __shared__ int  wsum[4];
    __shared__ int  sTot;

    const int side = blockIdx.y;
    const int tid  = threadIdx.x;
    const int lane = tid & 63, wid = tid >> 6;
    for (int i = tid; i < 512; i += 256) lhist[i] = 0;
    __syncthreads();

    const int c0 = blockIdx.x * PCH;
    int2 kvr[16];
    #pragma unroll
    for (int r = 0; r < 4; ++r) {
        int e0 = c0 + r * 1024 + tid * 4;
        int s4[4], d4[4];
        load_edges4(ei, E, Et, e0, s4, d4);
        #pragma unroll
        for (int k = 0; k < 4; ++k) {
            int key = side ? d4[k] : s4[k];
            int val = side ? s4[k] : d4[k];
            kvr[r * 4 + k] = make_int2(key, val);
            if (key >= 0) atomicAdd(&lhist[key >> BSH], 1);
        }
    }
    __syncthreads();

    // exclusive scan of 512 bucket counts (2 per thread)
    int a0 = lhist[2 * tid], a1 = lhist[2 * tid + 1];
    int pair = a0 + a1, s = pair;
    #pragma unroll
    for (int d = 1; d < 64; d <<= 1) {
        int t = __shfl_up(s, d);
        if (lane >= d) s += t;
    }
    if (lane == 63) wsum[wid] = s;
    __syncthreads();
    if (tid == 0) {
        int run = 0;
        #pragma unroll
        for (int i = 0; i < 4; ++i) { int t = wsum[i]; wsum[i] = run; run += t; }
    }
    __syncthreads();
    int exclT = s - pair + wsum[wid];
    int e0x = exclT, e1x = exclT + a0;
    if (tid == 255) sTot = e1x + a1;
    lhist[2 * tid]     = e0x;     // becomes local placement cursor
    lhist[2 * tid + 1] = e1x;
    if (a0 > 0) {
        int gb = atomicAdd(&cursor[side * BMAX + 2 * tid], a0);
        gbias[2 * tid] = gb - e0x;
    }
    if (a1 > 0) {
        int gb = atomicAdd(&cursor[side * BMAX + 2 * tid + 1], a1);
        gbias[2 * tid + 1] = gb - e1x;
    }
    __syncthreads();

    // place edges grouped by bucket in LDS
    #pragma unroll
    for (int k = 0; k < 16; ++k) {
        int key = kvr[k].x;
        if (key >= 0) {
            int lp = atomicAdd(&lhist[key >> BSH], 1);
            kv[lp] = kvr[k];
        }
    }
    __syncthreads();

    // grouped contiguous write-out
    const int tot = sTot;
    for (int i = tid; i < tot; i += 256) {
        int2 e = kv[i];
        int b = e.x >> BSH;
        Ag[(size_t)side * Et + gbias[b] + i] = e;
    }
}

// ---------------------------------------------------------------------------
// Final within-bucket sort + FUSED DENOM: one block per (bucket, side).
// Side 0 emits e2 (src-sorted). Side 1 sorts its dst-run srcs into an LDS
// mirror and immediately computes denom for its 128 dsts (per-dst start/end
// live in LDS, srcs read from LDS, a_src gathers coalesce per 33-thread
// group) -> writes ad2 {a_dst, 1/(denom+eps)}. The standalone denom kernel
// disappears; its gathers overlap with side-0 blocks. ss2 kept only as an
// overflow fallback (bucket > DCAP; mean bucket ~946).
// ---------------------------------------------------------------------------
__global__ __launch_bounds__(256) void p2_kernel(const int2* __restrict__ Ag,
                                                 const int* __restrict__ bbase,
                                                 int2* __restrict__ e2,
                                                 int* __restrict__ ss2,
                                                 const float* __restrict__ a_src,
                                                 const float* __restrict__ a_dstc,
                                                 float* __restrict__ ad2,
                                                 int N, int Et, int nb)
{
    const int side = blockIdx.y;
    const int b    = blockIdx.x;
    if (b >= nb) return;
    const int tid  = threadIdx.x;
    const int base = bbase[side * (BMAX + 1) + b];
    const int end  = bbase[side * (BMAX + 1) + b + 1];
    const int k0   = b << BSH;
    const int2* A  = Ag + (size_t)side * Et;

    __shared__ int lh[128];
    __shared__ int st[128];
    __shared__ int kvlds[DCAP];
    __shared__ int w0s;
    if (tid < 128) lh[tid] = 0;
    __syncthreads();
    for (int i = base + tid; i < end; i += 256)
        atomicAdd(&lh[A[i].x - k0], 1);
    __syncthreads();

    int v = 0, s = 0;
    if (tid < 128) {
        v = lh[tid]; s = v;
        #pragma unroll
        for (int d = 1; d < 64; d <<= 1) {
            int t = __shfl_up(s, d);
            if ((tid & 63) >= d) s += t;
        }
    }
    if (tid == 63) w0s = s;
    __syncthreads();
    if (tid >= 64 && tid < 128) s += w0s;
    int start = base + s - v;
    if (tid < 128) { st[tid] = start; lh[tid] = start; }   // per-id cursor
    __syncthreads();

    const int cnt = end - base;
    for (int i = base + tid; i < end; i += 256) {
        int2 e = A[i];
        int pos = atomicAdd(&lh[e.x - k0], 1);
        if (side == 0) e2[pos] = e;
        else {
            ss2[pos] = e.y;
            int l = pos - base;
            if (l < DCAP) kvlds[l] = e.y;
        }
    }
    if (side == 0) return;
    __syncthreads();   // kvlds + lh(end offsets) ready

    const bool lds_ok = (cnt <= DCAP);
    for (int p = tid; p < 128 * H_HEADS; p += 256) {
        int il = p / H_HEADS, h = p - il * H_HEADS;
        int id = k0 + il;
        if (id >= N) break;
        int b0 = st[il], b1 = lh[il];
        size_t g = (size_t)id * H_HEADS + h;
        float ad = a_dstc[g];
        float acc = 0.f;
        int e = b0;
        if (lds_ok) {
            for (; e + 4 <= b1; e += 4) {
                int s0 = kvlds[e - base],     s1 = kvlds[e - base + 1];
                int s2 = kvlds[e - base + 2], s3 = kvlds[e - base + 3];
                float v0 = a_src[(size_t)s0 * H_HEADS + h];
                float v1 = a_src[(size_t)s1 * H_HEADS + h];
                float v2 = a_src[(size_t)s2 * H_HEADS + h];
                float v3 = a_src[(size_t)s3 * H_HEADS + h];
                v0 += ad; v0 = v0 > 0.f ? v0 : NEG_SLOPE * v0;
                v1 += ad; v1 = v1 > 0.f ? v1 : NEG_SLOPE * v1;
                v2 += ad; v2 = v2 > 0.f ? v2 : NEG_SLOPE * v2;
                v3 += ad; v3 = v3 > 0.f ? v3 : NEG_SLOPE * v3;
                acc += __expf(v0); acc += __expf(v1);
                acc += __expf(v2); acc += __expf(v3);
            }
            for (; e < b1; ++e) {
                float vv = a_src[(size_t)kvlds[e - base] * H_HEADS + h] + ad;
                vv = vv > 0.f ? vv : NEG_SLOPE * vv;
                acc += __expf(vv);
            }
        } else {
            for (; e < b1; ++e) {
                float vv = a_src[(size_t)ss2[e] * H_HEADS + h] + ad;
                vv = vv > 0.f ? vv : NEG_SLOPE * vv;
                acc += __expf(vv);
            }
        }
        ((float2*)ad2)[g] = make_float2(ad, 1.0f / (acc + 1e-16f));
    }
}

// ---------------------------------------------------------------------------
// K3: 64 src-sorted edges/block. Phase 1 loads fenced ahead of the exps;
// phase 2 loads fenced ahead of a PACKED-FMA block: floatx2 accumulators
// emit v_pk_fma_f32 (2 FMAs/inst), cutting phase-2 VALU ~25% (round-10
// showed VALU is the dominant measured consumer at 42% busy).
// shfl-repack keeps 64B-covered atomics.
// ---------------------------------------------------------------------------
#define EPB 64
__global__ __launch_bounds__(256, 4) void aggregate_kernel(
    const int2* __restrict__ e2,
    const float* __restrict__ a_src, const float* __restrict__ ad2,
    const unsigned short* __restrict__ hb,
    float* __restrict__ out, int N, int Et)
{
    __shared__ int   s_src[EPB], s_dst[EPB];
    __shared__ float s_alpha[EPB][H_HEADS];

    // bijective XCD-chunked block swizzle (m204 formula)
    const int nwg = gridDim.x;
    const int q = nwg >> 3, r = nwg & 7;
    const int xcd = blockIdx.x & 7, idx = blockIdx.x >> 3;
    const int bid = (xcd < r ? xcd * (q + 1) : r * (q + 1) + (xcd - r) * q) + idx;

    const int tid = threadIdx.x;
    const int e0  = bid * EPB;
    const size_t segN = (size_t)N * 48;

    if (tid < EPB) {
        int e = e0 + tid;
        int2 v = (e < Et) ? e2[e] : make_int2(0, 0);
        s_src[tid] = v.x; s_dst[tid] = v.y;
    }
    __syncthreads();

    // phase 1: 64x33 = 2112 items = 8 full rounds + 64; loads fenced ahead.
    float2 di[9]; float as[9];
    #pragma unroll
    for (int rr = 0; rr < 8; ++rr) {
        int i = tid + rr * 256;
        int el = i / H_HEADS, hd = i - el * H_HEADS;
        di[rr] = ((const float2*)ad2)[(size_t)s_dst[el] * H_HEADS + hd];
        as[rr] = a_src[(size_t)s_src[el] * H_HEADS + hd];
    }
    if (tid < 64) {
        int i = 2048 + tid;
        int el = i / H_HEADS, hd = i - el * H_HEADS;
        di[8] = ((const float2*)ad2)[(size_t)s_dst[el] * H_HEADS + hd];
        as[8] = a_src[(size_t)s_src[el] * H_HEADS + hd];
    }
    __builtin_amdgcn_sched_barrier(0);   // all 18 loads issued before exps
    #pragma unroll
    for (int rr = 0; rr < 8; ++rr) {
        int i = tid + rr * 256;
        int el = i / H_HEADS, hd = i - el * H_HEADS;
        float v = as[rr] + di[rr].x;
        v = v > 0.f ? v : NEG_SLOPE * v;
        s_alpha[el][hd] = __expf(v) * di[rr].y;
    }
    if (tid < 64) {
        int i = 2048 + tid;
        int el = i / H_HEADS, hd = i - el * H_HEADS;
        float v = as[8] + di[8].x;
        v = v > 0.f ? v : NEG_SLOPE * v;
        s_alpha[el][hd] = __expf(v) * di[8].y;
    }
    __syncthreads();

    // phase 2: one edge per thread-quad, 4 channels per lane; all 33 uint2
    // loads issued before the packed-FMA block (sched_barrier fence).
    const int el = tid >> 2, cq = tid & 3;
    const int src = s_src[el];
    const unsigned short* hp = hb + (size_t)src * 48 + cq * 4;
    uint2 w[33];
    #pragma unroll
    for (int j = 0; j < JG; ++j) {
        const unsigned short* pj = hp + (size_t)j * segN;
        w[3 * j + 0] = *(const uint2*)(pj);
        w[3 * j + 1] = *(const uint2*)(pj + 16);
        w[3 * j + 2] = *(const uint2*)(pj + 32);
    }
    __builtin_amdgcn_sched_barrier(0);   // all 33 loads in flight before FMAs
    floatx2 acc01 = {0.f, 0.f}, acc23 = {0.f, 0.f};
    #pragma unroll
    for (int j = 0; j < JG; ++j) {
        float l0 = s_alpha[el][3 * j + 0];
        float l1 = s_alpha[el][3 * j + 1];
        float l2 = s_alpha[el][3 * j + 2];
        uint2 wA = w[3 * j], wB = w[3 * j + 1], wC = w[3 * j + 2];
        floatx2 hA0 = {bflo(wA.x), bfhi(wA.x)};
        floatx2 hB0 = {bflo(wB.x), bfhi(wB.x)};
        floatx2 hC0 = {bflo(wC.x), bfhi(wC.x)};
        floatx2 hA1 = {bflo(wA.y), bfhi(wA.y)};
        floatx2 hB1 = {bflo(wB.y), bfhi(wB.y)};
        floatx2 hC1 = {bflo(wC.y), bfhi(wC.y)};
        acc01 += hA0 * l0 + hB0 * l1 + hC0 * l2;   // v_pk_fma_f32
        acc23 += hA1 * l0 + hB1 * l1 + hC1 * l2;
    }
    float a0 = acc01.x, a1 = acc01.y, a2 = acc23.x, a3 = acc23.y;

    // shfl-repack: instr qx covers 4 edges x 16 contiguous channels (64B)
    const int lane  = tid & 63;
    const int wbase = (tid >> 6) * 16;       // first edge of this wave
    #pragma unroll
    for (int qx = 0; qx < 4; ++qx) {
        int S = 16 * qx + ((lane >> 4) << 2) + ((lane & 15) >> 2);
        float s0 = __shfl(a0, S), s1 = __shfl(a1, S);
        float s2 = __shfl(a2, S), s3 = __shfl(a3, S);
        float v = (lane & 2) ? ((lane & 1) ? s3 : s2)
                             : ((lane & 1) ? s1 : s0);
        int elT = wbase + qx * 4 + (lane >> 4);
        if (e0 + elT < Et)
            atomicAdd(&out[s_dst[elT] * C_CH + (lane & 15)], v);
    }
}

// K4: out = tanh(out/H + bias), in place
__global__ void finalize_kernel(float* __restrict__ out,
                                const float* __restrict__ bias, int total)
{
    int g = blockIdx.x * blockDim.x + threadIdx.x;
    if (g >= total) return;
    out[g] = tanhf(out[g] * (1.0f / 33.0f) + bias[g & 15]);
}

// ---------------------------------------------------------------------------
extern "C" void kernel_launch(void* const* d_in, const int* in_sizes, int n_in,
                              void* d_out, int out_size, void* d_ws, size_t ws_size,
                              hipStream_t stream)
{
    const float* x       = (const float*)d_in[0];
    const int*   ei      = (const int*)  d_in[1];
    const float* W       = (const float*)d_in[2];
    const float* att_src = (const float*)d_in[3];
    const float* att_dst = (const float*)d_in[4];
    const float* bias    = (const float*)d_in[5];
    float* out = (float*)d_out;

    const int N  = in_sizes[0] / F_IN;   // 50000
    const int E  = in_sizes[1] / 2;      // 320000
    const int Et = E + N;                // with self loops
    const int nb = (N + 127) >> BSH;     // 391 buckets

    // workspace layout (all 16B-aligned for these sizes)
    unsigned short* hb = (unsigned short*)d_ws;          // 11 segments [N][48]
    float* a_src  = (float*)(hb + (size_t)N * HC);       // [N][33]
    float* a_dstc = a_src + (size_t)N * H_HEADS;         // [N][33] compact a_dst
    float* ad2    = a_dstc + (size_t)N * H_HEADS;        // float2[N][33] a_dst|inv
    int2*  e2     = (int2*)(ad2 + (size_t)N * 66);       // [Et] (src,dst) src-sorted
    int*   ss2    = (int*)(e2 + Et);                     // [Et] src, dst-sorted (fallback)
    int2*  Ag     = (int2*)(ss2 + Et);                   // [2*Et] bucket-grouped
    int*   bhist  = (int*)(Ag + 2 * (size_t)Et);         // [2*BMAX]
    int*   bbase  = bhist + 2 * BMAX;                    // [2*(BMAX+1)]
    int*   cursor = bbase + 2 * (BMAX + 1);              // [2*BMAX]
    unsigned short* Wt = (unsigned short*)(cursor + 2 * BMAX);  // [624][128]

    // zero bucket hists before prep (prep does the hist atomics)
    hipMemsetAsync(bhist, 0, 2 * BMAX * sizeof(int), stream);

    const int nzo = out_size / 4;        // out zero in float4s
    const int EtC = (Et + 3) / 4;        // batched hist threads
    const int prepTot = PW2 + nzo + EtC;
    prep_kernel<<<(prepTot + 255) / 256, 256, 0, stream>>>(
        W, att_src, att_dst, Wt, (float4*)out, nzo, ei, bhist, E, Et);

    gemm_att_kernel<<<(N + 63) / 64, 256, 0, stream>>>(x, Wt, hb, a_src, a_dstc, N);

    scanb_kernel<<<2, 1024, 0, stream>>>(bhist, bbase, cursor, nb);
    part_kernel<<<dim3((Et + PCH - 1) / PCH, 2), 256, 0, stream>>>(
        ei, cursor, Ag, E, Et);
    p2_kernel<<<dim3(nb, 2), 256, 0, stream>>>(Ag, bbase, e2, ss2,
                                               a_src, a_dstc, ad2, N, Et, nb);

    aggregate_kernel<<<(Et + EPB - 1) / EPB, 256, 0, stream>>>(
        e2, a_src, ad2, hb, out, N, Et);

    int totO = N * C_CH;
    finalize_kernel<<<(totO + 255) / 256, 256, 0, stream>>>(out, bias, totO);
}

// Round 12
// 206.336 us; speedup vs baseline: 1.7966x; 1.7966x over previous
//
#include <hip/hip_runtime.h>
#include <math.h>

#define H_HEADS 33
#define C_CH    16
#define HC      528      // H_HEADS * C_CH
#define JG      11       // head groups of 3 (48 cols each) for h
#define JGT     13       // + 2 groups: att_src logits, att_dst logits
#define F_IN    128
#define NEG_SLOPE 0.2f

#define BSH   7          // bucket = id >> 7 (128 ids/bucket)
#define BMAX  1024       // max buckets supported (N <= 131072)
#define PCH   4096       // edges per partition block
#define DCAP  3072       // LDS mirror capacity in p2 (mean bucket ~946)

typedef short  bf16x8  __attribute__((ext_vector_type(8)));
typedef float  floatx4 __attribute__((ext_vector_type(4)));
typedef float  floatx2 __attribute__((ext_vector_type(2)));

__device__ inline unsigned short f2bf(float f) {   // RNE float->bf16
    unsigned int u = __float_as_uint(f);
    unsigned int r = u + 0x7fffu + ((u >> 16) & 1u);
    return (unsigned short)(r >> 16);
}
__device__ inline float bflo(unsigned int u) {
    return __uint_as_float(u << 16);
}
__device__ inline float bfhi(unsigned int u) {
    return __uint_as_float(u & 0xffff0000u);
}

// Load 4 consecutive (src,dst) edge pairs (self-loops appended past E).
// Sentinel -1 past Et.
__device__ inline void load_edges4(const int* __restrict__ ei, int E, int Et,
                                   int e0, int* src, int* dst)
{
    if (e0 + 3 < E) {
        int4 s4 = *(const int4*)&ei[e0];
        src[0] = s4.x; src[1] = s4.y; src[2] = s4.z; src[3] = s4.w;
        if ((E & 3) == 0) {
            int4 d4 = *(const int4*)&ei[E + e0];
            dst[0] = d4.x; dst[1] = d4.y; dst[2] = d4.z; dst[3] = d4.w;
        } else {
            #pragma unroll
            for (int k = 0; k < 4; ++k) dst[k] = ei[E + e0 + k];
        }
    } else {
        #pragma unroll
        for (int k = 0; k < 4; ++k) {
            int g = e0 + k;
            if (g < E)       { src[k] = ei[g]; dst[k] = ei[E + g]; }
            else if (g < Et) { src[k] = dst[k] = g - E; }
            else             { src[k] = dst[k] = -1; }
        }
    }
}

// ---------------------------------------------------------------------------
// K0: prep. (a) Wt[0..527] = bf16(W^T); (b) rows 528..623 = attention-logit
// GEMM columns; (c) zero out. (Bucket hist is a SEPARATE kernel: the coarse
// 782-counter histogram NEEDS per-block LDS pre-aggregation — round-11's
// fused version serialized 740K device atomics on 782 words, 171us.)
// ---------------------------------------------------------------------------
#define PW1 (F_IN * HC)        // 67584
#define PW2 (PW1 + 96 * F_IN)  // 79872
__global__ void prep_kernel(const float* __restrict__ W,
                            const float* __restrict__ att_src,
                            const float* __restrict__ att_dst,
                            unsigned short* __restrict__ Wt,
                            float4* __restrict__ zout, int nzo)
{
    int g = blockIdx.x * blockDim.x + threadIdx.x;
    if (g < PW1) {
        int k = g / HC, n = g % HC;
        Wt[n * F_IN + k] = f2bf(W[g]);
    } else if (g < PW2) {
        int gg = g - PW1;
        int nl = gg >> 7, k = gg & 127;
        int grp = nl / 48, h = nl % 48;
        float v = 0.f;
        if (h < H_HEADS) {
            const float* att = grp ? att_dst : att_src;
            const float* wr  = W + (size_t)k * HC + h * C_CH;
            #pragma unroll
            for (int c = 0; c < C_CH; ++c) v += wr[c] * att[h * C_CH + c];
        }
        Wt[(size_t)(HC + nl) * F_IN + k] = f2bf(v);
    } else {
        int z = g - PW2;
        if (z < nzo) zout[z] = make_float4(0.f, 0.f, 0.f, 0.f);
    }
}

// ---------------------------------------------------------------------------
// K1: h = x @ W via MFMA 16x16x32 bf16. As/Bs share one LDS buffer (As dead
// after A-fragment extraction): 17.4KB -> 8 blocks/CU. Bs staging register
// double-buffered. Groups 0..10 -> hb column-blocked [j][row][48];
// 11 -> a_src; 12 -> a_dstc.
// ---------------------------------------------------------------------------
#define LDA 136
__global__ __launch_bounds__(256) void gemm_att_kernel(
    const float* __restrict__ x, const unsigned short* __restrict__ Wt,
    unsigned short* __restrict__ hb,
    float* __restrict__ a_src, float* __restrict__ a_dstc, int N)
{
    __shared__ unsigned short U[64 * LDA];   // As (prologue) then Bs (loop)
    unsigned short (*As)[LDA] = (unsigned short (*)[LDA])U;
    unsigned short (*Bs)[LDA] = (unsigned short (*)[LDA])U;

    const int tid  = threadIdx.x;
    const int lane = tid & 63;
    const int wave = tid >> 6;
    const int lm   = lane & 15;
    const int kc   = lane >> 4;
    const int m0   = blockIdx.x * 64;
    const size_t segN = (size_t)N * 48;

    // stage As from f32 x, converting: 64 rows x 32 float4 chunks
    for (int e = tid; e < 64 * 32; e += 256) {
        int r = e >> 5, c = e & 31;
        int gr = m0 + r;
        float4 v = (gr < N) ? ((const float4*)(x + (size_t)gr * F_IN))[c]
                            : make_float4(0.f, 0.f, 0.f, 0.f);
        unsigned int lo = (unsigned int)f2bf(v.x) | ((unsigned int)f2bf(v.y) << 16);
        unsigned int hi = (unsigned int)f2bf(v.z) | ((unsigned int)f2bf(v.w) << 16);
        *(uint2*)&As[r][c * 4] = make_uint2(lo, hi);
    }

    // prefetch j=0 B-tile into registers (Wt rows are contiguous uint4s)
    const uint4* wp = (const uint4*)Wt;
    uint4 rb0 = wp[tid], rb1 = wp[tid + 256], rb2 = wp[tid + 512];

    __syncthreads();

    // A fragments to registers; As LDS space is dead after this (barrier at
    // the top of the j-loop orders these reads before the Bs overwrite)
    const int arow = wave * 16 + lm;
    bf16x8 afrag[4];
    #pragma unroll
    for (int ks = 0; ks < 4; ++ks)
        afrag[ks] = *(const bf16x8*)&As[arow][ks * 32 + kc * 8];

    #pragma unroll 1
    for (int j = 0; j < JGT; ++j) {
        __syncthreads();   // prev iter's Bs reads (and prologue As reads) done
        *(uint4*)&Bs[tid >> 4][(tid & 15) * 8] = rb0;
        { int e = tid + 256; *(uint4*)&Bs[e >> 4][(e & 15) * 8] = rb1; }
        { int e = tid + 512; *(uint4*)&Bs[e >> 4][(e & 15) * 8] = rb2; }
        if (j + 1 < JGT) {
            int b = (j + 1) * 768;
            rb0 = wp[b + tid]; rb1 = wp[b + tid + 256]; rb2 = wp[b + tid + 512];
        }
        __syncthreads();

        floatx4 acc[3] = {};
        #pragma unroll
        for (int ks = 0; ks < 4; ++ks) {
            #pragma unroll
            for (int t = 0; t < 3; ++t) {
                bf16x8 b = *(const bf16x8*)&Bs[t * 16 + lm][ks * 32 + kc * 8];
                acc[t] = __builtin_amdgcn_mfma_f32_16x16x32_bf16(afrag[ks], b, acc[t], 0, 0, 0);
            }
        }

        // C/D layout: col = lane&15, row = (lane>>4)*4 + reg
        #pragma unroll
        for (int t = 0; t < 3; ++t) {
            #pragma unroll
            for (int rr = 0; rr < 4; ++rr) {
                const int row = m0 + wave * 16 + kc * 4 + rr;
                if (row >= N) continue;
                if (j < JG) {
                    hb[(size_t)j * segN + (size_t)row * 48 + t * 16 + lm] =
                        f2bf(acc[t][rr]);
                } else {
                    const int col = t * 16 + lm;
                    if (col < H_HEADS) {
                        float* dstp = (j == JG) ? a_src : a_dstc;
                        dstp[(size_t)row * H_HEADS + col] = acc[t][rr];
                    }
                }
            }
        }
    }
}

// ---------------------------------------------------------------------------
// Bucket histograms (src>>BSH and dst>>BSH), LDS-preaggregated: <=2048
// global atomics per block instead of per-edge device atomics (essential —
// 740K device atomics on 782 words serialize to ~170us).
// ---------------------------------------------------------------------------
__global__ __launch_bounds__(256) void bhist_kernel(const int* __restrict__ ei,
                                                    int* __restrict__ bhist,
                                                    int E, int Et)
{
    __shared__ int lh[2 * BMAX];
    const int tid = threadIdx.x;
    for (int i = tid; i < 2 * BMAX; i += 256) lh[i] = 0;
    __syncthreads();
    int e0 = (blockIdx.x * 256 + tid) * 8;
    if (e0 < Et) {
        int s4[4], d4[4];
        #pragma unroll
        for (int h = 0; h < 2; ++h) {
            load_edges4(ei, E, Et, e0 + h * 4, s4, d4);
            #pragma unroll
            for (int k = 0; k < 4; ++k)
                if (s4[k] >= 0) {
                    atomicAdd(&lh[s4[k] >> BSH], 1);
                    atomicAdd(&lh[BMAX + (d4[k] >> BSH)], 1);
                }
        }
    }
    __syncthreads();
    for (int i = tid; i < 2 * BMAX; i += 256) {
        int v = lh[i];
        if (v) atomicAdd(&bhist[i], v);
    }
}

// ---------------------------------------------------------------------------
// Bucket scan: grid=2 (side 0 = src, side 1 = dst).
// ---------------------------------------------------------------------------
__global__ __launch_bounds__(1024) void scanb_kernel(const int* __restrict__ bhist,
                                                     int* __restrict__ bbase,
                                                     int* __restrict__ cursor,
                                                     int nb)
{
    const int side = blockIdx.x;
    const int tid  = threadIdx.x;
    const int* h = bhist + side * BMAX;
    int* bb  = bbase  + side * (BMAX + 1);
    int* cur = cursor + side * BMAX;
    __shared__ int sa[1024];
    int v = (tid < nb) ? h[tid] : 0;
    sa[tid] = v;
    __syncthreads();
    for (int off = 1; off < 1024; off <<= 1) {
        int t = (tid >= off) ? sa[tid - off] : 0;
        __syncthreads();
        sa[tid] += t;
        __syncthreads();
    }
    int incl = sa[tid];
    if (tid < nb) {
        bb[tid]  = incl - v;
        cur[tid] = incl - v;
        if (tid == nb - 1) bb[nb] = incl;
    }
}

// ---------------------------------------------------------------------------
// Partition pass: block takes PCH edges, groups by bucket in LDS, reserves
// per-bucket global space (one atomic per block-bucket), writes groups
// contiguously (full sectors).
// ---------------------------------------------------------------------------
__global__ __launch_bounds__(256) void part_kernel(const int* __restrict__ ei,
                                                   int* __restrict__ cursor,
                                                   int2* __restrict__ Ag,
                                                   int E, int Et)
{
    __shared__ int2 kv[PCH];
    __shared__ int  lhist[512];
    __shared__ int  gbias[512];
    __shared__ int  wsum[4];
    __shared__ int  sTot;

    const int side = blockIdx.y;
    const int tid  = threadIdx.x;
    const int lane = tid & 63, wid = tid >> 6;
    for (int i = tid; i < 512; i += 256) lhist[i] = 0;
    __syncthreads();

    const int c0 = blockIdx.x * PCH;
    int2 kvr[16];
    #pragma unroll
    for (int r = 0; r < 4; ++r) {
        int e0 = c0 + r * 1024 + tid * 4;
        int s4[4], d4[4];
        load_edges4(ei, E, Et, e0, s4, d4);
        #pragma unroll
        for (int k = 0; k < 4; ++k) {
            int key = side ? d4[k] : s4[k];
            int val = side ? s4[k] : d4[k];
            kvr[r * 4 + k] = make_int2(key, val);
            if (key >= 0) atomicAdd(&lhist[key >> BSH], 1);
        }
    }
    __syncthreads();

    // exclusive scan of 512 bucket counts (2 per thread)
    int a0 = lhist[2 * tid], a1 = lhist[2 * tid + 1];
    int pair = a0 + a1, s = pair;
    #pragma unroll
    for (int d = 1; d < 64; d <<= 1) {
        int t = __shfl_up(s, d);
        if (lane >= d) s += t;
    }
    if (lane == 63) wsum[wid] = s;
    __syncthreads();
    if (tid == 0) {
        int run = 0;
        #pragma unroll
        for (int i = 0; i < 4; ++i) { int t = wsum[i]; wsum[i] = run; run += t; }
    }
    __syncthreads();
    int exclT = s - pair + wsum[wid];
    int e0x = exclT, e1x = exclT + a0;
    if (tid == 255) sTot = e1x + a1;
    lhist[2 * tid]     = e0x;     // becomes local placement cursor
    lhist[2 * tid + 1] = e1x;
    if (a0 > 0) {
        int gb = atomicAdd(&cursor[side * BMAX + 2 * tid], a0);
        gbias[2 * tid] = gb - e0x;
    }
    if (a1 > 0) {
        int gb = atomicAdd(&cursor[side * BMAX + 2 * tid + 1], a1);
        gbias[2 * tid + 1] = gb - e1x;
    }
    __syncthreads();

    // place edges grouped by bucket in LDS
    #pragma unroll
    for (int k = 0; k < 16; ++k) {
        int key = kvr[k].x;
        if (key >= 0) {
            int lp = atomicAdd(&lhist[key >> BSH], 1);
            kv[lp] = kvr[k];
        }
    }
    __syncthreads();

    // grouped contiguous write-out
    const int tot = sTot;
    for (int i = tid; i < tot; i += 256) {
        int2 e = kv[i];
        int b = e.x >> BSH;
        Ag[(size_t)side * Et + gbias[b] + i] = e;
    }
}

// ---------------------------------------------------------------------------
// Final within-bucket sort + FUSED DENOM: one block per (bucket, side).
// Side 0 emits e2 (src-sorted). Side 1 sorts its dst-run srcs into an LDS
// mirror and immediately computes denom for its 128 dsts -> writes ad2
// {a_dst, 1/(denom+eps)}. ss2 kept only as overflow fallback (> DCAP).
// ---------------------------------------------------------------------------
__global__ __launch_bounds__(256) void p2_kernel(const int2* __restrict__ Ag,
                                                 const int* __restrict__ bbase,
                                                 int2* __restrict__ e2,
                                                 int* __restrict__ ss2,
                                                 const float* __restrict__ a_src,
                                                 const float* __restrict__ a_dstc,
                                                 float* __restrict__ ad2,
                                                 int N, int Et, int nb)
{
    const int side = blockIdx.y;
    const int b    = blockIdx.x;
    if (b >= nb) return;
    const int tid  = threadIdx.x;
    const int base = bbase[side * (BMAX + 1) + b];
    const int end  = bbase[side * (BMAX + 1) + b + 1];
    const int k0   = b << BSH;
    const int2* A  = Ag + (size_t)side * Et;

    __shared__ int lh[128];
    __shared__ int st[128];
    __shared__ int kvlds[DCAP];
    __shared__ int w0s;
    if (tid < 128) lh[tid] = 0;
    __syncthreads();
    for (int i = base + tid; i < end; i += 256)
        atomicAdd(&lh[A[i].x - k0], 1);
    __syncthreads();

    int v = 0, s = 0;
    if (tid < 128) {
        v = lh[tid]; s = v;
        #pragma unroll
        for (int d = 1; d < 64; d <<= 1) {
            int t = __shfl_up(s, d);
            if ((tid & 63) >= d) s += t;
        }
    }
    if (tid == 63) w0s = s;
    __syncthreads();
    if (tid >= 64 && tid < 128) s += w0s;
    int start = base + s - v;
    if (tid < 128) { st[tid] = start; lh[tid] = start; }   // per-id cursor
    __syncthreads();

    const int cnt = end - base;
    for (int i = base + tid; i < end; i += 256) {
        int2 e = A[i];
        int pos = atomicAdd(&lh[e.x - k0], 1);
        if (side == 0) e2[pos] = e;
        else {
            ss2[pos] = e.y;
            int l = pos - base;
            if (l < DCAP) kvlds[l] = e.y;
        }
    }
    if (side == 0) return;
    __syncthreads();   // kvlds + lh(end offsets) ready

    const bool lds_ok = (cnt <= DCAP);
    for (int p = tid; p < 128 * H_HEADS; p += 256) {
        int il = p / H_HEADS, h = p - il * H_HEADS;
        int id = k0 + il;
        if (id >= N) break;
        int b0 = st[il], b1 = lh[il];
        size_t g = (size_t)id * H_HEADS + h;
        float ad = a_dstc[g];
        float acc = 0.f;
        int e = b0;
        if (lds_ok) {
            for (; e + 4 <= b1; e += 4) {
                int s0 = kvlds[e - base],     s1 = kvlds[e - base + 1];
                int s2 = kvlds[e - base + 2], s3 = kvlds[e - base + 3];
                float v0 = a_src[(size_t)s0 * H_HEADS + h];
                float v1 = a_src[(size_t)s1 * H_HEADS + h];
                float v2 = a_src[(size_t)s2 * H_HEADS + h];
                float v3 = a_src[(size_t)s3 * H_HEADS + h];
                v0 += ad; v0 = v0 > 0.f ? v0 : NEG_SLOPE * v0;
                v1 += ad; v1 = v1 > 0.f ? v1 : NEG_SLOPE * v1;
                v2 += ad; v2 = v2 > 0.f ? v2 : NEG_SLOPE * v2;
                v3 += ad; v3 = v3 > 0.f ? v3 : NEG_SLOPE * v3;
                acc += __expf(v0); acc += __expf(v1);
                acc += __expf(v2); acc += __expf(v3);
            }
            for (; e < b1; ++e) {
                float vv = a_src[(size_t)kvlds[e - base] * H_HEADS + h] + ad;
                vv = vv > 0.f ? vv : NEG_SLOPE * vv;
                acc += __expf(vv);
            }
        } else {
            for (; e < b1; ++e) {
                float vv = a_src[(size_t)ss2[e] * H_HEADS + h] + ad;
                vv = vv > 0.f ? vv : NEG_SLOPE * vv;
                acc += __expf(vv);
            }
        }
        ((float2*)ad2)[g] = make_float2(ad, 1.0f / (acc + 1e-16f));
    }
}

// ---------------------------------------------------------------------------
// K3: 64 src-sorted edges/block. Phase 1 loads fenced ahead of the exps;
// phase 2 loads fenced ahead of a PACKED-FMA block (v_pk_fma_f32).
// shfl-repack keeps 64B-covered atomics.
// ---------------------------------------------------------------------------
#define EPB 64
__global__ __launch_bounds__(256, 4) void aggregate_kernel(
    const int2* __restrict__ e2,
    const float* __restrict__ a_src, const float* __restrict__ ad2,
    const unsigned short* __restrict__ hb,
    float* __restrict__ out, int N, int Et)
{
    __shared__ int   s_src[EPB], s_dst[EPB];
    __shared__ float s_alpha[EPB][H_HEADS];

    // bijective XCD-chunked block swizzle (m204 formula)
    const int nwg = gridDim.x;
    const int q = nwg >> 3, r = nwg & 7;
    const int xcd = blockIdx.x & 7, idx = blockIdx.x >> 3;
    const int bid = (xcd < r ? xcd * (q + 1) : r * (q + 1) + (xcd - r) * q) + idx;

    const int tid = threadIdx.x;
    const int e0  = bid * EPB;
    const size_t segN = (size_t)N * 48;

    if (tid < EPB) {
        int e = e0 + tid;
        int2 v = (e < Et) ? e2[e] : make_int2(0, 0);
        s_src[tid] = v.x; s_dst[tid] = v.y;
    }
    __syncthreads();

    // phase 1: 64x33 = 2112 items = 8 full rounds + 64; loads fenced ahead.
    float2 di[9]; float as[9];
    #pragma unroll
    for (int rr = 0; rr < 8; ++rr) {
        int i = tid + rr * 256;
        int el = i / H_HEADS, hd = i - el * H_HEADS;
        di[rr] = ((const float2*)ad2)[(size_t)s_dst[el] * H_HEADS + hd];
        as[rr] = a_src[(size_t)s_src[el] * H_HEADS + hd];
    }
    if (tid < 64) {
        int i = 2048 + tid;
        int el = i / H_HEADS, hd = i - el * H_HEADS;
        di[8] = ((const float2*)ad2)[(size_t)s_dst[el] * H_HEADS + hd];
        as[8] = a_src[(size_t)s_src[el] * H_HEADS + hd];
    }
    __builtin_amdgcn_sched_barrier(0);   // all 18 loads issued before exps
    #pragma unroll
    for (int rr = 0; rr < 8; ++rr) {
        int i = tid + rr * 256;
        int el = i / H_HEADS, hd = i - el * H_HEADS;
        float v = as[rr] + di[rr].x;
        v = v > 0.f ? v : NEG_SLOPE * v;
        s_alpha[el][hd] = __expf(v) * di[rr].y;
    }
    if (tid < 64) {
        int i = 2048 + tid;
        int el = i / H_HEADS, hd = i - el * H_HEADS;
        float v = as[8] + di[8].x;
        v = v > 0.f ? v : NEG_SLOPE * v;
        s_alpha[el][hd] = __expf(v) * di[8].y;
    }
    __syncthreads();

    // phase 2: one edge per thread-quad, 4 channels per lane; all 33 uint2
    // loads issued before the packed-FMA block (sched_barrier fence).
    const int el = tid >> 2, cq = tid & 3;
    const int src = s_src[el];
    const unsigned short* hp = hb + (size_t)src * 48 + cq * 4;
    uint2 w[33];
    #pragma unroll
    for (int j = 0; j < JG; ++j) {
        const unsigned short* pj = hp + (size_t)j * segN;
        w[3 * j + 0] = *(const uint2*)(pj);
        w[3 * j + 1] = *(const uint2*)(pj + 16);
        w[3 * j + 2] = *(const uint2*)(pj + 32);
    }
    __builtin_amdgcn_sched_barrier(0);   // all 33 loads in flight before FMAs
    floatx2 acc01 = {0.f, 0.f}, acc23 = {0.f, 0.f};
    #pragma unroll
    for (int j = 0; j < JG; ++j) {
        float l0 = s_alpha[el][3 * j + 0];
        float l1 = s_alpha[el][3 * j + 1];
        float l2 = s_alpha[el][3 * j + 2];
        uint2 wA = w[3 * j], wB = w[3 * j + 1], wC = w[3 * j + 2];
        floatx2 hA0 = {bflo(wA.x), bfhi(wA.x)};
        floatx2 hB0 = {bflo(wB.x), bfhi(wB.x)};
        floatx2 hC0 = {bflo(wC.x), bfhi(wC.x)};
        floatx2 hA1 = {bflo(wA.y), bfhi(wA.y)};
        floatx2 hB1 = {bflo(wB.y), bfhi(wB.y)};
        floatx2 hC1 = {bflo(wC.y), bfhi(wC.y)};
        acc01 += hA0 * l0 + hB0 * l1 + hC0 * l2;   // v_pk_fma_f32
        acc23 += hA1 * l0 + hB1 * l1 + hC1 * l2;
    }
    float a0 = acc01.x, a1 = acc01.y, a2 = acc23.x, a3 = acc23.y;

    // shfl-repack: instr qx covers 4 edges x 16 contiguous channels (64B)
    const int lane  = tid & 63;
    const int wbase = (tid >> 6) * 16;       // first edge of this wave
    #pragma unroll
    for (int qx = 0; qx < 4; ++qx) {
        int S = 16 * qx + ((lane >> 4) << 2) + ((lane & 15) >> 2);
        float s0 = __shfl(a0, S), s1 = __shfl(a1, S);
        float s2 = __shfl(a2, S), s3 = __shfl(a3, S);
        float v = (lane & 2) ? ((lane & 1) ? s3 : s2)
                             : ((lane & 1) ? s1 : s0);
        int elT = wbase + qx * 4 + (lane >> 4);
        if (e0 + elT < Et)
            atomicAdd(&out[s_dst[elT] * C_CH + (lane & 15)], v);
    }
}

// K4: out = tanh(out/H + bias), in place
__global__ void finalize_kernel(float* __restrict__ out,
                                const float* __restrict__ bias, int total)
{
    int g = blockIdx.x * blockDim.x + threadIdx.x;
    if (g >= total) return;
    out[g] = tanhf(out[g] * (1.0f / 33.0f) + bias[g & 15]);
}

// ---------------------------------------------------------------------------
extern "C" void kernel_launch(void* const* d_in, const int* in_sizes, int n_in,
                              void* d_out, int out_size, void* d_ws, size_t ws_size,
                              hipStream_t stream)
{
    const float* x       = (const float*)d_in[0];
    const int*   ei      = (const int*)  d_in[1];
    const float* W       = (const float*)d_in[2];
    const float* att_src = (const float*)d_in[3];
    const float* att_dst = (const float*)d_in[4];
    const float* bias    = (const float*)d_in[5];
    float* out = (float*)d_out;

    const int N  = in_sizes[0] / F_IN;   // 50000
    const int E  = in_sizes[1] / 2;      // 320000
    const int Et = E + N;                // with self loops
    const int nb = (N + 127) >> BSH;     // 391 buckets

    // workspace layout (all 16B-aligned for these sizes)
    unsigned short* hb = (unsigned short*)d_ws;          // 11 segments [N][48]
    float* a_src  = (float*)(hb + (size_t)N * HC);       // [N][33]
    float* a_dstc = a_src + (size_t)N * H_HEADS;         // [N][33] compact a_dst
    float* ad2    = a_dstc + (size_t)N * H_HEADS;        // float2[N][33] a_dst|inv
    int2*  e2     = (int2*)(ad2 + (size_t)N * 66);       // [Et] (src,dst) src-sorted
    int*   ss2    = (int*)(e2 + Et);                     // [Et] src, dst-sorted (fallback)
    int2*  Ag     = (int2*)(ss2 + Et);                   // [2*Et] bucket-grouped
    int*   bhist  = (int*)(Ag + 2 * (size_t)Et);         // [2*BMAX]
    int*   bbase  = bhist + 2 * BMAX;                    // [2*(BMAX+1)]
    int*   cursor = bbase + 2 * (BMAX + 1);              // [2*BMAX]
    unsigned short* Wt = (unsigned short*)(cursor + 2 * BMAX);  // [624][128]

    // zero bucket hists before bhist_kernel
    hipMemsetAsync(bhist, 0, 2 * BMAX * sizeof(int), stream);

    const int nzo = out_size / 4;        // out zero in float4s
    const int prepTot = PW2 + nzo;
    prep_kernel<<<(prepTot + 255) / 256, 256, 0, stream>>>(
        W, att_src, att_dst, Wt, (float4*)out, nzo);

    gemm_att_kernel<<<(N + 63) / 64, 256, 0, stream>>>(x, Wt, hb, a_src, a_dstc, N);

    bhist_kernel<<<(Et + 2047) / 2048, 256, 0, stream>>>(ei, bhist, E, Et);
    scanb_kernel<<<2, 1024, 0, stream>>>(bhist, bbase, cursor, nb);
    part_kernel<<<dim3((Et + PCH - 1) / PCH, 2), 256, 0, stream>>>(
        ei, cursor, Ag, E, Et);
    p2_kernel<<<dim3(nb, 2), 256, 0, stream>>>(Ag, bbase, e2, ss2,
                                               a_src, a_dstc, ad2, N, Et, nb);

    aggregate_kernel<<<(Et + EPB - 1) / EPB, 256, 0, stream>>>(
        e2, a_src, ad2, hb, out, N, Et);

    int totO = N * C_CH;
    finalize_kernel<<<(totO + 255) / 256, 256, 0, stream>>>(out, bias, totO);
}

// Round 13
// 188.753 us; speedup vs baseline: 1.9639x; 1.0932x over previous
//
#include <hip/hip_runtime.h>
#include <math.h>

#define H_HEADS 33
#define C_CH    16
#define HC      528      // H_HEADS * C_CH
#define JG      11       // head groups of 3 (48 cols each) for h
#define JGT     13       // + 2 groups: att_src logits, att_dst logits
#define F_IN    128
#define NEG_SLOPE 0.2f

#define BSH   7          // bucket = id >> 7 (128 ids/bucket)
#define BMAX  1024       // max buckets supported (N <= 131072)
#define PCH   4096       // edges per partition block

typedef short  bf16x8  __attribute__((ext_vector_type(8)));
typedef float  floatx4 __attribute__((ext_vector_type(4)));
typedef float  floatx2 __attribute__((ext_vector_type(2)));

__device__ inline unsigned short f2bf(float f) {   // RNE float->bf16
    unsigned int u = __float_as_uint(f);
    unsigned int r = u + 0x7fffu + ((u >> 16) & 1u);
    return (unsigned short)(r >> 16);
}
__device__ inline float bflo(unsigned int u) {
    return __uint_as_float(u << 16);
}
__device__ inline float bfhi(unsigned int u) {
    return __uint_as_float(u & 0xffff0000u);
}

// Load 4 consecutive (src,dst) edge pairs (self-loops appended past E).
// Sentinel -1 past Et.
__device__ inline void load_edges4(const int* __restrict__ ei, int E, int Et,
                                   int e0, int* src, int* dst)
{
    if (e0 + 3 < E) {
        int4 s4 = *(const int4*)&ei[e0];
        src[0] = s4.x; src[1] = s4.y; src[2] = s4.z; src[3] = s4.w;
        if ((E & 3) == 0) {
            int4 d4 = *(const int4*)&ei[E + e0];
            dst[0] = d4.x; dst[1] = d4.y; dst[2] = d4.z; dst[3] = d4.w;
        } else {
            #pragma unroll
            for (int k = 0; k < 4; ++k) dst[k] = ei[E + e0 + k];
        }
    } else {
        #pragma unroll
        for (int k = 0; k < 4; ++k) {
            int g = e0 + k;
            if (g < E)       { src[k] = ei[g]; dst[k] = ei[E + g]; }
            else if (g < Et) { src[k] = dst[k] = g - E; }
            else             { src[k] = dst[k] = -1; }
        }
    }
}

// ---------------------------------------------------------------------------
// K0: prep. (a) Wt[0..527] = bf16(W^T); (b) rows 528..623 = attention-logit
// GEMM columns; (c) zero out.
// ---------------------------------------------------------------------------
#define PW1 (F_IN * HC)        // 67584
#define PW2 (PW1 + 96 * F_IN)  // 79872
__global__ void prep_kernel(const float* __restrict__ W,
                            const float* __restrict__ att_src,
                            const float* __restrict__ att_dst,
                            unsigned short* __restrict__ Wt,
                            float4* __restrict__ zout, int nzo)
{
    int g = blockIdx.x * blockDim.x + threadIdx.x;
    if (g < PW1) {
        int k = g / HC, n = g % HC;
        Wt[n * F_IN + k] = f2bf(W[g]);
    } else if (g < PW2) {
        int gg = g - PW1;
        int nl = gg >> 7, k = gg & 127;
        int grp = nl / 48, h = nl % 48;
        float v = 0.f;
        if (h < H_HEADS) {
            const float* att = grp ? att_dst : att_src;
            const float* wr  = W + (size_t)k * HC + h * C_CH;
            #pragma unroll
            for (int c = 0; c < C_CH; ++c) v += wr[c] * att[h * C_CH + c];
        }
        Wt[(size_t)(HC + nl) * F_IN + k] = f2bf(v);
    } else {
        int z = g - PW2;
        if (z < nzo) zout[z] = make_float4(0.f, 0.f, 0.f, 0.f);
    }
}

// ---------------------------------------------------------------------------
// K1: h = x @ W via MFMA 16x16x32 bf16. As/Bs share one LDS buffer (As dead
// after A-fragment extraction): 17.4KB -> 8 blocks/CU. Bs staging register
// double-buffered. Groups 0..10 -> hb column-blocked [j][row][48];
// 11 -> a_src; 12 -> a_dstc.
// ---------------------------------------------------------------------------
#define LDA 136
__global__ __launch_bounds__(256) void gemm_att_kernel(
    const float* __restrict__ x, const unsigned short* __restrict__ Wt,
    unsigned short* __restrict__ hb,
    float* __restrict__ a_src, float* __restrict__ a_dstc, int N)
{
    __shared__ unsigned short U[64 * LDA];   // As (prologue) then Bs (loop)
    unsigned short (*As)[LDA] = (unsigned short (*)[LDA])U;
    unsigned short (*Bs)[LDA] = (unsigned short (*)[LDA])U;

    const int tid  = threadIdx.x;
    const int lane = tid & 63;
    const int wave = tid >> 6;
    const int lm   = lane & 15;
    const int kc   = lane >> 4;
    const int m0   = blockIdx.x * 64;
    const size_t segN = (size_t)N * 48;

    // stage As from f32 x, converting: 64 rows x 32 float4 chunks
    for (int e = tid; e < 64 * 32; e += 256) {
        int r = e >> 5, c = e & 31;
        int gr = m0 + r;
        float4 v = (gr < N) ? ((const float4*)(x + (size_t)gr * F_IN))[c]
                            : make_float4(0.f, 0.f, 0.f, 0.f);
        unsigned int lo = (unsigned int)f2bf(v.x) | ((unsigned int)f2bf(v.y) << 16);
        unsigned int hi = (unsigned int)f2bf(v.z) | ((unsigned int)f2bf(v.w) << 16);
        *(uint2*)&As[r][c * 4] = make_uint2(lo, hi);
    }

    // prefetch j=0 B-tile into registers (Wt rows are contiguous uint4s)
    const uint4* wp = (const uint4*)Wt;
    uint4 rb0 = wp[tid], rb1 = wp[tid + 256], rb2 = wp[tid + 512];

    __syncthreads();

    // A fragments to registers; As LDS space is dead after this (barrier at
    // the top of the j-loop orders these reads before the Bs overwrite)
    const int arow = wave * 16 + lm;
    bf16x8 afrag[4];
    #pragma unroll
    for (int ks = 0; ks < 4; ++ks)
        afrag[ks] = *(const bf16x8*)&As[arow][ks * 32 + kc * 8];

    #pragma unroll 1
    for (int j = 0; j < JGT; ++j) {
        __syncthreads();   // prev iter's Bs reads (and prologue As reads) done
        *(uint4*)&Bs[tid >> 4][(tid & 15) * 8] = rb0;
        { int e = tid + 256; *(uint4*)&Bs[e >> 4][(e & 15) * 8] = rb1; }
        { int e = tid + 512; *(uint4*)&Bs[e >> 4][(e & 15) * 8] = rb2; }
        if (j + 1 < JGT) {
            int b = (j + 1) * 768;
            rb0 = wp[b + tid]; rb1 = wp[b + tid + 256]; rb2 = wp[b + tid + 512];
        }
        __syncthreads();

        floatx4 acc[3] = {};
        #pragma unroll
        for (int ks = 0; ks < 4; ++ks) {
            #pragma unroll
            for (int t = 0; t < 3; ++t) {
                bf16x8 b = *(const bf16x8*)&Bs[t * 16 + lm][ks * 32 + kc * 8];
                acc[t] = __builtin_amdgcn_mfma_f32_16x16x32_bf16(afrag[ks], b, acc[t], 0, 0, 0);
            }
        }

        // C/D layout: col = lane&15, row = (lane>>4)*4 + reg
        #pragma unroll
        for (int t = 0; t < 3; ++t) {
            #pragma unroll
            for (int rr = 0; rr < 4; ++rr) {
                const int row = m0 + wave * 16 + kc * 4 + rr;
                if (row >= N) continue;
                if (j < JG) {
                    hb[(size_t)j * segN + (size_t)row * 48 + t * 16 + lm] =
                        f2bf(acc[t][rr]);
                } else {
                    const int col = t * 16 + lm;
                    if (col < H_HEADS) {
                        float* dstp = (j == JG) ? a_src : a_dstc;
                        dstp[(size_t)row * H_HEADS + col] = acc[t][rr];
                    }
                }
            }
        }
    }
}

// ---------------------------------------------------------------------------
// Bucket histograms (src>>BSH and dst>>BSH), LDS-preaggregated (essential).
// ---------------------------------------------------------------------------
__global__ __launch_bounds__(256) void bhist_kernel(const int* __restrict__ ei,
                                                    int* __restrict__ bhist,
                                                    int E, int Et)
{
    __shared__ int lh[2 * BMAX];
    const int tid = threadIdx.x;
    for (int i = tid; i < 2 * BMAX; i += 256) lh[i] = 0;
    __syncthreads();
    int e0 = (blockIdx.x * 256 + tid) * 8;
    if (e0 < Et) {
        int s4[4], d4[4];
        #pragma unroll
        for (int h = 0; h < 2; ++h) {
            load_edges4(ei, E, Et, e0 + h * 4, s4, d4);
            #pragma unroll
            for (int k = 0; k < 4; ++k)
                if (s4[k] >= 0) {
                    atomicAdd(&lh[s4[k] >> BSH], 1);
                    atomicAdd(&lh[BMAX + (d4[k] >> BSH)], 1);
                }
        }
    }
    __syncthreads();
    for (int i = tid; i < 2 * BMAX; i += 256) {
        int v = lh[i];
        if (v) atomicAdd(&bhist[i], v);
    }
}

// ---------------------------------------------------------------------------
// Bucket scan: grid=2 (side 0 = src, side 1 = dst).
// ---------------------------------------------------------------------------
__global__ __launch_bounds__(1024) void scanb_kernel(const int* __restrict__ bhist,
                                                     int* __restrict__ bbase,
                                                     int* __restrict__ cursor,
                                                     int nb)
{
    const int side = blockIdx.x;
    const int tid  = threadIdx.x;
    const int* h = bhist + side * BMAX;
    int* bb  = bbase  + side * (BMAX + 1);
    int* cur = cursor + side * BMAX;
    __shared__ int sa[1024];
    int v = (tid < nb) ? h[tid] : 0;
    sa[tid] = v;
    __syncthreads();
    for (int off = 1; off < 1024; off <<= 1) {
        int t = (tid >= off) ? sa[tid - off] : 0;
        __syncthreads();
        sa[tid] += t;
        __syncthreads();
    }
    int incl = sa[tid];
    if (tid < nb) {
        bb[tid]  = incl - v;
        cur[tid] = incl - v;
        if (tid == nb - 1) bb[nb] = incl;
    }
}

// ---------------------------------------------------------------------------
// Partition pass: block takes PCH edges, groups by bucket in LDS, reserves
// per-bucket global space (one atomic per block-bucket), writes groups
// contiguously (full sectors).
// ---------------------------------------------------------------------------
__global__ __launch_bounds__(256) void part_kernel(const int* __restrict__ ei,
                                                   int* __restrict__ cursor,
                                                   int2* __restrict__ Ag,
                                                   int E, int Et)
{
    __shared__ int2 kv[PCH];
    __shared__ int  lhist[512];
    __shared__ int  gbias[512];
    __shared__ int  wsum[4];
    __shared__ int  sTot;

    const int side = blockIdx.y;
    const int tid  = threadIdx.x;
    const int lane = tid & 63, wid = tid >> 6;
    for (int i = tid; i < 512; i += 256) lhist[i] = 0;
    __syncthreads();

    const int c0 = blockIdx.x * PCH;
    int2 kvr[16];
    #pragma unroll
    for (int r = 0; r < 4; ++r) {
        int e0 = c0 + r * 1024 + tid * 4;
        int s4[4], d4[4];
        load_edges4(ei, E, Et, e0, s4, d4);
        #pragma unroll
        for (int k = 0; k < 4; ++k) {
            int key = side ? d4[k] : s4[k];
            int val = side ? s4[k] : d4[k];
            kvr[r * 4 + k] = make_int2(key, val);
            if (key >= 0) atomicAdd(&lhist[key >> BSH], 1);
        }
    }
    __syncthreads();

    // exclusive scan of 512 bucket counts (2 per thread)
    int a0 = lhist[2 * tid], a1 = lhist[2 * tid + 1];
    int pair = a0 + a1, s = pair;
    #pragma unroll
    for (int d = 1; d < 64; d <<= 1) {
        int t = __shfl_up(s, d);
        if (lane >= d) s += t;
    }
    if (lane == 63) wsum[wid] = s;
    __syncthreads();
    if (tid == 0) {
        int run = 0;
        #pragma unroll
        for (int i = 0; i < 4; ++i) { int t = wsum[i]; wsum[i] = run; run += t; }
    }
    __syncthreads();
    int exclT = s - pair + wsum[wid];
    int e0x = exclT, e1x = exclT + a0;
    if (tid == 255) sTot = e1x + a1;
    lhist[2 * tid]     = e0x;     // becomes local placement cursor
    lhist[2 * tid + 1] = e1x;
    if (a0 > 0) {
        int gb = atomicAdd(&cursor[side * BMAX + 2 * tid], a0);
        gbias[2 * tid] = gb - e0x;
    }
    if (a1 > 0) {
        int gb = atomicAdd(&cursor[side * BMAX + 2 * tid + 1], a1);
        gbias[2 * tid + 1] = gb - e1x;
    }
    __syncthreads();

    // place edges grouped by bucket in LDS
    #pragma unroll
    for (int k = 0; k < 16; ++k) {
        int key = kvr[k].x;
        if (key >= 0) {
            int lp = atomicAdd(&lhist[key >> BSH], 1);
            kv[lp] = kvr[k];
        }
    }
    __syncthreads();

    // grouped contiguous write-out
    const int tot = sTot;
    for (int i = tid; i < tot; i += 256) {
        int2 e = kv[i];
        int b = e.x >> BSH;
        Ag[(size_t)side * Et + gbias[b] + i] = e;
    }
}

// ---------------------------------------------------------------------------
// Final within-bucket sort: one block per (bucket, side). Side 1 also emits
// off_d coalesced. (Denom stays a SEPARATE kernel: round-12's fusion
// concentrated denom work into 391 blocks -> parallelism collapse, +13us.)
// ---------------------------------------------------------------------------
__global__ __launch_bounds__(256) void p2_kernel(const int2* __restrict__ Ag,
                                                 const int* __restrict__ bbase,
                                                 int2* __restrict__ e2,
                                                 int* __restrict__ ss2,
                                                 int* __restrict__ off_d,
                                                 int N, int Et, int nb)
{
    const int side = blockIdx.y;
    const int b    = blockIdx.x;
    if (b >= nb) return;
    const int tid  = threadIdx.x;
    const int base = bbase[side * (BMAX + 1) + b];
    const int end  = bbase[side * (BMAX + 1) + b + 1];
    const int k0   = b << BSH;
    const int2* A  = Ag + (size_t)side * Et;

    __shared__ int lh[128];
    __shared__ int w0s;
    if (tid < 128) lh[tid] = 0;
    __syncthreads();
    for (int i = base + tid; i < end; i += 256)
        atomicAdd(&lh[A[i].x - k0], 1);
    __syncthreads();

    int v = 0, s = 0;
    if (tid < 128) {
        v = lh[tid]; s = v;
        #pragma unroll
        for (int d = 1; d < 64; d <<= 1) {
            int t = __shfl_up(s, d);
            if ((tid & 63) >= d) s += t;
        }
    }
    if (tid == 63) w0s = s;
    __syncthreads();
    if (tid >= 64 && tid < 128) s += w0s;
    int start = base + s - v;
    if (tid < 128) {
        lh[tid] = start;                       // per-id cursor
        if (side == 1 && (k0 + tid) < N) off_d[k0 + tid] = start;
    }
    __syncthreads();

    for (int i = base + tid; i < end; i += 256) {
        int2 e = A[i];
        int pos = atomicAdd(&lh[e.x - k0], 1);
        if (side == 0) e2[pos] = e;
        else           ss2[pos] = e.y;
    }
}

// ---------------------------------------------------------------------------
// K2: denom, atomic-free, thread-per-(dst,head), 4-wide pipelined gather.
// Writes interleaved float2 {a_dst, 1/(denom+eps)}.
// ---------------------------------------------------------------------------
__global__ __launch_bounds__(256) void denom_kernel(
    const int* __restrict__ off_d, const int* __restrict__ ss2,
    const float* __restrict__ a_src, const float* __restrict__ a_dstc,
    float* __restrict__ ad2, int N, int Et)
{
    int g = blockIdx.x * blockDim.x + threadIdx.x;
    if (g >= N * H_HEADS) return;
    const int d = g / H_HEADS, h = g - d * H_HEADS;
    const int beg = off_d[d];
    const int end = (d + 1 < N) ? off_d[d + 1] : Et;
    const float ad = a_dstc[g];
    float acc = 0.f;
    int e = beg;
    for (; e + 4 <= end; e += 4) {
        int s0 = ss2[e], s1 = ss2[e + 1], s2 = ss2[e + 2], s3 = ss2[e + 3];
        float v0 = a_src[(size_t)s0 * H_HEADS + h];
        float v1 = a_src[(size_t)s1 * H_HEADS + h];
        float v2 = a_src[(size_t)s2 * H_HEADS + h];
        float v3 = a_src[(size_t)s3 * H_HEADS + h];
        v0 += ad; v0 = v0 > 0.f ? v0 : NEG_SLOPE * v0;
        v1 += ad; v1 = v1 > 0.f ? v1 : NEG_SLOPE * v1;
        v2 += ad; v2 = v2 > 0.f ? v2 : NEG_SLOPE * v2;
        v3 += ad; v3 = v3 > 0.f ? v3 : NEG_SLOPE * v3;
        acc += __expf(v0); acc += __expf(v1);
        acc += __expf(v2); acc += __expf(v3);
    }
    for (; e < end; ++e) {
        float v = a_src[(size_t)ss2[e] * H_HEADS + h] + ad;
        v = v > 0.f ? v : NEG_SLOPE * v;
        acc += __expf(v);
    }
    ((float2*)ad2)[g] = make_float2(ad, 1.0f / (acc + 1e-16f));
}

// ---------------------------------------------------------------------------
// K3: 64 src-sorted edges/block + LDS ROW-STAGING. A block's 64 sorted edges
// share ~9 distinct src rows (avg deg 7.4): wave 0 detects runs via ballot,
// then up to RCAP=20 distinct hb rows are staged cooperatively (66 coalesced
// uint4 each) into LDS. Phase-2's 33 gathers per quad-lane become broadcast
// ds_read_b64 (~6-12cy) instead of L1/L2 global gathers (~200cy) — the
// orthogonal lever after 3 flat MLP attempts (VGPR stuck at 40, both pipes
// <50%). Rows past RCAP fall back to global loads (rare).
// ---------------------------------------------------------------------------
#define EPB  64
#define RCAP 20
#define RSTR 536   // LDS row stride in shorts (1072B: 16B-aligned, 12-bank skew)
__global__ __launch_bounds__(256, 4) void aggregate_kernel(
    const int2* __restrict__ e2,
    const float* __restrict__ a_src, const float* __restrict__ ad2,
    const unsigned short* __restrict__ hb,
    float* __restrict__ out, int N, int Et)
{
    __shared__ int   s_src[EPB], s_dst[EPB];
    __shared__ float s_alpha[EPB][H_HEADS];
    __shared__ int   s_ridx[EPB];
    __shared__ int   s_rowsrc[RCAP];
    __shared__ int   s_U;
    __shared__ __align__(16) unsigned short Hrow[RCAP * RSTR];

    // bijective XCD-chunked block swizzle (m204 formula)
    const int nwg = gridDim.x;
    const int q = nwg >> 3, r = nwg & 7;
    const int xcd = blockIdx.x & 7, idx = blockIdx.x >> 3;
    const int bid = (xcd < r ? xcd * (q + 1) : r * (q + 1) + (xcd - r) * q) + idx;

    const int tid = threadIdx.x;
    const int e0  = bid * EPB;
    const size_t segN = (size_t)N * 48;

    if (tid < EPB) {
        int e = e0 + tid;
        int2 v = (e < Et) ? e2[e] : make_int2(0, 0);
        s_src[tid] = v.x; s_dst[tid] = v.y;
    }
    __syncthreads();

    // run detection (wave 0, one lane per edge)
    if (tid < 64) {
        int src = s_src[tid];
        bool flag = (tid == 0) || (src != s_src[tid - 1]);
        unsigned long long b = __ballot(flag);
        int cntb = __popcll(b & ((1ull << tid) - 1));   // flags strictly below
        int run  = flag ? cntb : cntb - 1;
        s_ridx[tid] = (run < RCAP) ? run : -1;
        if (flag && run < RCAP) s_rowsrc[run] = src;
        if (tid == 63) s_U = __popcll(b);
    }
    __syncthreads();

    // stage distinct rows: U x 66 uint4 chunks (row = 11 segments x 96B)
    int Un = s_U; if (Un > RCAP) Un = RCAP;
    for (int i = tid; i < Un * 66; i += 256) {
        int rr = i / 66, c = i - rr * 66;
        int j = c / 6, qq = c - j * 6;
        int srcr = s_rowsrc[rr];
        uint4 v = *(const uint4*)(hb + (size_t)j * segN + (size_t)srcr * 48 + qq * 8);
        *(uint4*)&Hrow[rr * RSTR + j * 48 + qq * 8] = v;
    }

    // phase 1: 64x33 = 2112 items = 8 full rounds + 64; loads fenced ahead.
    float2 di[9]; float as[9];
    #pragma unroll
    for (int rr = 0; rr < 8; ++rr) {
        int i = tid + rr * 256;
        int el = i / H_HEADS, hd = i - el * H_HEADS;
        di[rr] = ((const float2*)ad2)[(size_t)s_dst[el] * H_HEADS + hd];
        as[rr] = a_src[(size_t)s_src[el] * H_HEADS + hd];
    }
    if (tid < 64) {
        int i = 2048 + tid;
        int el = i / H_HEADS, hd = i - el * H_HEADS;
        di[8] = ((const float2*)ad2)[(size_t)s_dst[el] * H_HEADS + hd];
        as[8] = a_src[(size_t)s_src[el] * H_HEADS + hd];
    }
    __builtin_amdgcn_sched_barrier(0);
    #pragma unroll
    for (int rr = 0; rr < 8; ++rr) {
        int i = tid + rr * 256;
        int el = i / H_HEADS, hd = i - el * H_HEADS;
        float v = as[rr] + di[rr].x;
        v = v > 0.f ? v : NEG_SLOPE * v;
        s_alpha[el][hd] = __expf(v) * di[rr].y;
    }
    if (tid < 64) {
        int i = 2048 + tid;
        int el = i / H_HEADS, hd = i - el * H_HEADS;
        float v = as[8] + di[8].x;
        v = v > 0.f ? v : NEG_SLOPE * v;
        s_alpha[el][hd] = __expf(v) * di[8].y;
    }
    __syncthreads();   // s_alpha + Hrow ready

    // phase 2: one edge per thread-quad, 4 channels per lane
    const int el = tid >> 2, cq = tid & 3;
    const int rid = s_ridx[el];
    floatx2 acc01 = {0.f, 0.f}, acc23 = {0.f, 0.f};
    if (rid >= 0) {
        const unsigned short* pr = &Hrow[rid * RSTR + cq * 4];
        #pragma unroll
        for (int j = 0; j < JG; ++j) {
            uint2 wA = *(const uint2*)(pr + j * 48);
            uint2 wB = *(const uint2*)(pr + j * 48 + 16);
            uint2 wC = *(const uint2*)(pr + j * 48 + 32);
            float l0 = s_alpha[el][3 * j + 0];
            float l1 = s_alpha[el][3 * j + 1];
            float l2 = s_alpha[el][3 * j + 2];
            floatx2 hA0 = {bflo(wA.x), bfhi(wA.x)};
            floatx2 hB0 = {bflo(wB.x), bfhi(wB.x)};
            floatx2 hC0 = {bflo(wC.x), bfhi(wC.x)};
            floatx2 hA1 = {bflo(wA.y), bfhi(wA.y)};
            floatx2 hB1 = {bflo(wB.y), bfhi(wB.y)};
            floatx2 hC1 = {bflo(wC.y), bfhi(wC.y)};
            acc01 += hA0 * l0 + hB0 * l1 + hC0 * l2;   // v_pk_fma_f32
            acc23 += hA1 * l0 + hB1 * l1 + hC1 * l2;
        }
    } else {   // rare fallback: row not staged
        const unsigned short* hp = hb + (size_t)s_src[el] * 48 + cq * 4;
        #pragma unroll
        for (int j = 0; j < JG; ++j) {
            const unsigned short* pj = hp + (size_t)j * segN;
            uint2 wA = *(const uint2*)(pj);
            uint2 wB = *(const uint2*)(pj + 16);
            uint2 wC = *(const uint2*)(pj + 32);
            float l0 = s_alpha[el][3 * j + 0];
            float l1 = s_alpha[el][3 * j + 1];
            float l2 = s_alpha[el][3 * j + 2];
            floatx2 hA0 = {bflo(wA.x), bfhi(wA.x)};
            floatx2 hB0 = {bflo(wB.x), bfhi(wB.x)};
            floatx2 hC0 = {bflo(wC.x), bfhi(wC.x)};
            floatx2 hA1 = {bflo(wA.y), bfhi(wA.y)};
            floatx2 hB1 = {bflo(wB.y), bfhi(wB.y)};
            floatx2 hC1 = {bflo(wC.y), bfhi(wC.y)};
            acc01 += hA0 * l0 + hB0 * l1 + hC0 * l2;
            acc23 += hA1 * l0 + hB1 * l1 + hC1 * l2;
        }
    }
    float a0 = acc01.x, a1 = acc01.y, a2 = acc23.x, a3 = acc23.y;

    // shfl-repack: instr qx covers 4 edges x 16 contiguous channels (64B)
    const int lane  = tid & 63;
    const int wbase = (tid >> 6) * 16;       // first edge of this wave
    #pragma unroll
    for (int qx = 0; qx < 4; ++qx) {
        int S = 16 * qx + ((lane >> 4) << 2) + ((lane & 15) >> 2);
        float s0 = __shfl(a0, S), s1 = __shfl(a1, S);
        float s2 = __shfl(a2, S), s3 = __shfl(a3, S);
        float v = (lane & 2) ? ((lane & 1) ? s3 : s2)
                             : ((lane & 1) ? s1 : s0);
        int elT = wbase + qx * 4 + (lane >> 4);
        if (e0 + elT < Et)
            atomicAdd(&out[s_dst[elT] * C_CH + (lane & 15)], v);
    }
}

// K4: out = tanh(out/H + bias), in place
__global__ void finalize_kernel(float* __restrict__ out,
                                const float* __restrict__ bias, int total)
{
    int g = blockIdx.x * blockDim.x + threadIdx.x;
    if (g >= total) return;
    out[g] = tanhf(out[g] * (1.0f / 33.0f) + bias[g & 15]);
}

// ---------------------------------------------------------------------------
extern "C" void kernel_launch(void* const* d_in, const int* in_sizes, int n_in,
                              void* d_out, int out_size, void* d_ws, size_t ws_size,
                              hipStream_t stream)
{
    const float* x       = (const float*)d_in[0];
    const int*   ei      = (const int*)  d_in[1];
    const float* W       = (const float*)d_in[2];
    const float* att_src = (const float*)d_in[3];
    const float* att_dst = (const float*)d_in[4];
    const float* bias    = (const float*)d_in[5];
    float* out = (float*)d_out;

    const int N  = in_sizes[0] / F_IN;   // 50000
    const int E  = in_sizes[1] / 2;      // 320000
    const int Et = E + N;                // with self loops
    const int nb = (N + 127) >> BSH;     // 391 buckets

    // workspace layout (all 16B-aligned for these sizes)
    unsigned short* hb = (unsigned short*)d_ws;          // 11 segments [N][48]
    float* a_src  = (float*)(hb + (size_t)N * HC);       // [N][33]
    float* a_dstc = a_src + (size_t)N * H_HEADS;         // [N][33] compact a_dst
    float* ad2    = a_dstc + (size_t)N * H_HEADS;        // float2[N][33] a_dst|inv
    int2*  e2     = (int2*)(ad2 + (size_t)N * 66);       // [Et] (src,dst) src-sorted
    int*   ss2    = (int*)(e2 + Et);                     // [Et] src, dst-sorted
    int*   off_d  = ss2 + Et;                            // [N]
    int2*  Ag     = (int2*)(off_d + N);                  // [2*Et] bucket-grouped
    int*   bhist  = (int*)(Ag + 2 * (size_t)Et);         // [2*BMAX]
    int*   bbase  = bhist + 2 * BMAX;                    // [2*(BMAX+1)]
    int*   cursor = bbase + 2 * (BMAX + 1);              // [2*BMAX]
    unsigned short* Wt = (unsigned short*)(cursor + 2 * BMAX);  // [624][128]

    // zero bucket hists before bhist_kernel
    hipMemsetAsync(bhist, 0, 2 * BMAX * sizeof(int), stream);

    const int nzo = out_size / 4;        // out zero in float4s
    const int prepTot = PW2 + nzo;
    prep_kernel<<<(prepTot + 255) / 256, 256, 0, stream>>>(
        W, att_src, att_dst, Wt, (float4*)out, nzo);

    gemm_att_kernel<<<(N + 63) / 64, 256, 0, stream>>>(x, Wt, hb, a_src, a_dstc, N);

    bhist_kernel<<<(Et + 2047) / 2048, 256, 0, stream>>>(ei, bhist, E, Et);
    scanb_kernel<<<2, 1024, 0, stream>>>(bhist, bbase, cursor, nb);
    part_kernel<<<dim3((Et + PCH - 1) / PCH, 2), 256, 0, stream>>>(
        ei, cursor, Ag, E, Et);
    p2_kernel<<<dim3(nb, 2), 256, 0, stream>>>(Ag, bbase, e2, ss2, off_d,
                                               N, Et, nb);

    denom_kernel<<<(N * H_HEADS + 255) / 256, 256, 0, stream>>>(
        off_d, ss2, a_src, a_dstc, ad2, N, Et);

    aggregate_kernel<<<(Et + EPB - 1) / EPB, 256, 0, stream>>>(
        e2, a_src, ad2, hb, out, N, Et);

    int totO = N * C_CH;
    finalize_kernel<<<(totO + 255) / 256, 256, 0, stream>>>(out, bias, totO);
}